// Round 1
// baseline (436.550 us; speedup 1.0000x reference)
//
#include <hip/hip_runtime.h>

typedef __bf16 bf16;
typedef __attribute__((ext_vector_type(8))) __bf16 bf16x8;
typedef __attribute__((ext_vector_type(4))) float f32x4;

#define MEMFENCE asm volatile("" ::: "memory")

// async global->LDS, 16B per lane; LDS dest = wave-uniform base + lane*16
__device__ __forceinline__ void gload16(const bf16* g, bf16* l) {
    __builtin_amdgcn_global_load_lds(
        (const __attribute__((address_space(1))) void*)g,
        (__attribute__((address_space(3))) void*)l,
        16, 0, 0);
}

// ================= 256x256 8-wave bf16 NT GEMM, BK=64, 8-phase, A triple-buffered ==========
// LDS map (160 KiB exactly): A bufs {0,1,2} at a*32768 (96K), B bufs {0,1} at 98304+p*32768 (64K).
// Per K-tile u (B buf p=u&1, A buf u%3), 4 phases, each: [stage 1 half-tile][ds_reads][barrier]
// [setprio+16 MFMA+setprio][barrier].  Quadrants: ph1 (mf0-3,nf0-1) reads a-lo,b-lo (12);
// ph2 (mf0-3,nf2-3) reads b-hi (4); ph3 (mf4-7,nf2-3) reads a-hi (8); ph4 (mf4-7,nf0-1) (0).
// Stages (all u+2 ahead): ph1/ph2 -> A0/A1(u+2) into buf (u+2)%3; ph3/ph4 -> B0/B1(u+2) buf p.
// vmcnt(8) at ph4 only: queue is [B(u+1)4, A(u+2)4, B(u+2)4] -> confirms B(u+1) (and A(u+1),
// confirmed one tile earlier), leaves A(u+2)+B(u+2)'s 8 loads in flight.  A's issue->confirm
// slack is ~10 phases (was ~2.5): HBM-latency staging misses no longer stall ph4.
// st_16x32 swizzle: phys = off ^ (((off>>9)&1)<<5); inverse-swizzled global source.
// EPI 0: bf16 C = alpha*acc
// EPI 1: bf16 C[ix] = aux3[ix] * (acc - aux1[zb*2048+row])      (dS = A*(dA-rowdot), in-place ok)
// EPI 2: f32  C = aux1[ix] + (float)aux3[ix] - alpha*acc        (out = V + AO - eps*scale*dQacc)
template<int EPI>
__global__ __launch_bounds__(512, 1)
void gemm8p(const bf16* __restrict__ A, const bf16* __restrict__ Bm,
            void* __restrict__ Cp, int Kdim, int lda, int ldb, int ldc,
            long sA, long sB, long sC, float alpha,
            const float* __restrict__ aux1, const bf16* __restrict__ aux3)
{
    __shared__ __align__(16) char smem[163840];

    // XCD-aware bijective swizzle (ntot % 8 == 0 for all launches)
    const int gx = gridDim.x, gy = gridDim.y;
    int lin = blockIdx.x + gx * (blockIdx.y + gy * blockIdx.z);
    const int q = (gx * gy * gridDim.z) >> 3;
    lin = (lin & 7) * q + (lin >> 3);
    const int bx = lin % gx;
    const int rem0 = lin / gx;
    const int by = rem0 % gy;
    const int bz = rem0 / gy;

    const int t0 = threadIdx.x;
    const int w = t0 >> 6, lane = t0 & 63;
    const int wm = w >> 2, wn = w & 3;          // 2 x 4 wave grid; per-wave C = 128 x 64
    const int m0 = by * 256, n0 = bx * 256;
    const long zb = bz;

    const bf16* Ab = A  + zb * sA + (size_t)m0 * lda;
    const bf16* Bb = Bm + zb * sB + (size_t)n0 * ldb;

    // staging lane coords: wave w stages subtiles {w, 8+w} of a 128-row half-tile
    const int sr16 = lane >> 2;
    const int sce  = ((((lane & 3) << 4) ^ (((lane >> 5) & 1) << 5))) >> 1; // inv-swizzled col
    const int r0s = (w >> 1) * 16 + sr16;
    const int c0s = (w & 1) * 32 + sce;
    const bf16* gA0 = Ab + (size_t)r0s * lda + c0s;
    const bf16* gA1 = Ab + (size_t)(128 + r0s) * lda + c0s;
    const bf16* gB0 = Bb + (size_t)r0s * ldb + c0s;
    const bf16* gB1 = Bb + (size_t)(128 + r0s) * ldb + c0s;
    const size_t a64 = (size_t)64 * lda, b64 = (size_t)64 * ldb;
    const int ldsW0 = w * 1024, ldsW1 = (8 + w) * 1024;

    // fragment-read bases (16x16x32 layout)
    const int lr = lane & 15, lkq = lane >> 4;
    const int phx = ((lane >> 3) & 1) << 5;
    const int frag_base = (lr * 64 + lkq * 16) ^ phx;
    const char* aR = smem + wm * 16384 + frag_base;                    // + aOff + sub*1024
    const char* bR = smem + 98304 + (wn >> 1) * 16384 + (wn & 1) * 8192 + frag_base; // + p*32768

    f32x4 acc[8][4] = {};
    const int NTt = Kdim >> 6;                  // K-tiles of 64 (8/16/32, always even)

    auto stgA = [&](int h, int u, int off) {
        char* L = smem + off + h * 16384;
        const bf16* g = h ? gA1 : gA0;
        gload16(g + (size_t)u * 64,        (bf16*)(L + ldsW0));
        gload16(g + a64 + (size_t)u * 64,  (bf16*)(L + ldsW1));
    };
    auto stgB = [&](int h, int u, int p) {
        char* L = smem + 98304 + p * 32768 + h * 16384;
        const bf16* g = h ? gB1 : gB0;
        gload16(g + (size_t)u * 64,        (bf16*)(L + ldsW0));
        gload16(g + b64 + (size_t)u * 64,  (bf16*)(L + ldsW1));
    };

    // ---- prologue: A(0),B(0) then A(1),B(1); confirm A(0),B(0); leave A(1)+B(1) in flight ----
    stgA(0, 0, 0);     stgA(1, 0, 0);     stgB(0, 0, 0); stgB(1, 0, 0);
    stgA(0, 1, 32768); stgA(1, 1, 32768); stgB(0, 1, 1); stgB(1, 1, 1);
    asm volatile("s_waitcnt vmcnt(8)" ::: "memory");
    __builtin_amdgcn_s_barrier();
    MEMFENCE;

    bf16x8 a[4][2], b[4][2];

#define QUAD(MFB, NFB)                                                                  \
    __builtin_amdgcn_s_setprio(1);                                                      \
    _Pragma("unroll")                                                                   \
    for (int ks = 0; ks < 2; ++ks)                                                      \
        _Pragma("unroll")                                                               \
        for (int mf = 0; mf < 4; ++mf)                                                  \
            _Pragma("unroll")                                                           \
            for (int nf = 0; nf < 2; ++nf)                                              \
                acc[(MFB) + mf][(NFB) + nf] = __builtin_amdgcn_mfma_f32_16x16x32_bf16(  \
                    a[mf][ks], b[(NFB) + nf][ks], acc[(MFB) + mf][(NFB) + nf], 0, 0, 0);\
    __builtin_amdgcn_s_setprio(0);

    int aOff = 0, sOff = 65536;                 // read buf u%3, stage buf (u+2)%3
    for (int u = 0; u < NTt; ++u) {
        const int p = u & 1;
        const char* aP = aR + aOff;
        const char* bP = bR + p * 32768;
        const bool st2 = (u + 2 < NTt);

        // ---- ph1: quadrant (mf0-3, nf0-1); 12 ds_reads; stage A0(u+2) ----
        if (st2) stgA(0, u + 2, sOff);
        #pragma unroll
        for (int mf = 0; mf < 4; ++mf)
            #pragma unroll
            for (int ks = 0; ks < 2; ++ks)
                a[mf][ks] = *(const bf16x8*)(aP + (mf * 2 + ks) * 1024);
        #pragma unroll
        for (int nf = 0; nf < 2; ++nf)
            #pragma unroll
            for (int ks = 0; ks < 2; ++ks)
                b[nf][ks] = *(const bf16x8*)(bP + (nf * 2 + ks) * 1024);
        MEMFENCE;
        __builtin_amdgcn_s_barrier();
        QUAD(0, 0)
        MEMFENCE;
        __builtin_amdgcn_s_barrier();

        // ---- ph2: quadrant (mf0-3, nf2-3); 4 ds_reads; stage A1(u+2) ----
        if (st2) stgA(1, u + 2, sOff);
        #pragma unroll
        for (int nf = 2; nf < 4; ++nf)
            #pragma unroll
            for (int ks = 0; ks < 2; ++ks)
                b[nf][ks] = *(const bf16x8*)(bP + (nf * 2 + ks) * 1024);
        MEMFENCE;
        __builtin_amdgcn_s_barrier();
        QUAD(0, 2)
        MEMFENCE;
        __builtin_amdgcn_s_barrier();

        // ---- ph3: quadrant (mf4-7, nf2-3); 8 ds_reads; stage B0(u+2) ----
        if (st2) stgB(0, u + 2, p);
        #pragma unroll
        for (int mf = 0; mf < 4; ++mf)
            #pragma unroll
            for (int ks = 0; ks < 2; ++ks)
                a[mf][ks] = *(const bf16x8*)(aP + ((4 + mf) * 2 + ks) * 1024);
        MEMFENCE;
        __builtin_amdgcn_s_barrier();
        QUAD(4, 2)
        MEMFENCE;
        __builtin_amdgcn_s_barrier();

        // ---- ph4: quadrant (mf4-7, nf0-1); 0 ds_reads; stage B1(u+2); vmcnt ladder ----
        if (st2) stgB(1, u + 2, p);
        MEMFENCE;
        if (st2) asm volatile("s_waitcnt vmcnt(8)" ::: "memory");
        else     asm volatile("s_waitcnt vmcnt(0)" ::: "memory");
        __builtin_amdgcn_s_barrier();
        QUAD(4, 0)
        MEMFENCE;
        __builtin_amdgcn_s_barrier();
        MEMFENCE;

        aOff = (aOff == 65536) ? 0 : aOff + 32768;
        sOff = (sOff == 65536) ? 0 : sOff + 32768;
    }
#undef QUAD

    // ---- epilogue: D layout col=lane&15, row=(lane>>4)*4+reg ----
    const int rb  = m0 + wm * 128 + lkq * 4;
    const int cb0 = n0 + wn * 64 + lr;
    #pragma unroll
    for (int mf = 0; mf < 8; ++mf) {
        #pragma unroll
        for (int r = 0; r < 4; ++r) {
            const int rw = rb + mf * 16 + r;
            float rd = 0.f;
            if (EPI == 1) rd = aux1[zb * 2048 + rw];
            #pragma unroll
            for (int nf = 0; nf < 4; ++nf) {
                const int c = cb0 + nf * 16;
                const size_t ix = (size_t)rw * ldc + c;
                const float v = acc[mf][nf][r];
                if (EPI == 0) {
                    ((bf16*)Cp + zb * sC)[ix] = (bf16)(alpha * v);
                } else if (EPI == 1) {
                    bf16* Cb = (bf16*)Cp + zb * sC;
                    const bf16* Am = aux3 + zb * sC;
                    Cb[ix] = (bf16)((float)Am[ix] * (v - rd));
                } else {
                    float* C = (float*)Cp + zb * sC;
                    const float* Vv = aux1 + zb * sC;
                    const bf16* AOv = aux3 + zb * sC;
                    C[ix] = Vv[ix] + (float)AOv[ix] - alpha * v;
                }
            }
        }
    }
}

// ===== round-6 engine: 256 x (64*NF) quad-slot BK=32 cross-step =====
// EPI 0: bf16 C = alpha*acc
// EPI 3: bf16 C = silu'(acc + aux1[col]) * aux2[col];  H[ix] = (bf16)acc  (H via aux3, cast)
template<int EPI, int NF>
__global__ __launch_bounds__(512, 1)
void gemm_nc(const bf16* __restrict__ A, const bf16* __restrict__ Bm,
             void* __restrict__ Cp, int Kdim, int lda, int ldb, int ldc,
             long sA, long sB, long sC, float alpha,
             const float* __restrict__ aux1, const float* __restrict__ aux2,
             const bf16* __restrict__ aux3)
{
    constexpr int SB = NF * 4096;
    __shared__ __align__(16) char smem[65536 + 4 * SB];

    const int gx = gridDim.x, gy = gridDim.y;
    int lin = blockIdx.x + gx * (blockIdx.y + gy * blockIdx.z);
    const int q = (gx * gy * gridDim.z) >> 3;
    lin = (lin & 7) * q + (lin >> 3);
    const int bx = lin % gx;
    const int rem0 = lin / gx;
    const int by = rem0 % gy;
    const int bz = rem0 / gy;

    const int t0 = threadIdx.x;
    const int w = t0 >> 6, lane = t0 & 63;
    const int wm = w >> 2, wn = w & 3;
    const int m0 = by * 256, n0 = bx * (64 * NF);
    const long zb = bz;

    const bf16* Ab = A  + zb * sA + (size_t)m0 * lda;
    const bf16* Bb = Bm + zb * sB + (size_t)n0 * ldb;

    const int sr16 = lane >> 2;
    const int sce  = ((((lane & 3) << 4) ^ (((lane >> 5) & 1) << 5))) >> 1;
    const int stg0 = w * 2, stg1 = w * 2 + 1;
    const bf16* pA0 = Ab + (size_t)(stg0 * 16 + sr16) * lda + sce;
    const bf16* pA1 = Ab + (size_t)(stg1 * 16 + sr16) * lda + sce;
    const bf16* pB0 = Bb + (size_t)((NF == 4 ? stg0 : w) * 16 + sr16) * ldb + sce;
    const bf16* pB1 = Bb + (size_t)(stg1 * 16 + sr16) * ldb + sce;

    const int lr = lane & 15, lkq = lane >> 4;
    const int phx = ((lane >> 3) & 1) << 5;
    const int frag_base = lr * 64 + lkq * 16;

    f32x4 acc[8][NF] = {};
    const int NT = Kdim >> 5;

    auto issueSlot = [&](int p) {
        char* lA = smem + (p & 3) * 16384;
        char* lB = smem + 65536 + (p & 3) * SB;
        const int kt = p << 5;
        gload16(pA0 + kt, (bf16*)(lA + stg0 * 1024));
        gload16(pA1 + kt, (bf16*)(lA + stg1 * 1024));
        if (NF == 4) {
            gload16(pB0 + kt, (bf16*)(lB + stg0 * 1024));
            gload16(pB1 + kt, (bf16*)(lB + stg1 * 1024));
        } else {
            gload16(pB0 + kt, (bf16*)(lB + w * 1024));
        }
    };
    auto rdA = [&](const char* base, int sub) {
        return *(const bf16x8*)(base + (((sub << 10) + frag_base) ^ phx));
    };

    issueSlot(0); issueSlot(1); issueSlot(2);
    if (NF == 4) asm volatile("s_waitcnt vmcnt(4)" ::: "memory");
    else         asm volatile("s_waitcnt vmcnt(3)" ::: "memory");
    __builtin_amdgcn_s_barrier();
    MEMFENCE;

    bf16x8 alo[4], ahi[4], b0[NF], b1[NF];
    {
        const char* cA = smem;
        const char* cB = smem + 65536;
        #pragma unroll
        for (int mf = 0; mf < 4; ++mf) alo[mf] = rdA(cA, wm * 8 + mf);
        #pragma unroll
        for (int nf = 0; nf < NF; ++nf) b0[nf] = rdA(cB, wn * NF + nf);
    }

    auto stepBody = [&](int SL, int s, bf16x8 (&bA)[NF], bf16x8 (&bB)[NF]) {
        if (s + 3 < NT) issueSlot(s + 3);
        const char* cA = smem + SL * 16384;
        #pragma unroll
        for (int mf = 0; mf < 4; ++mf) ahi[mf] = rdA(cA, wm * 8 + 4 + mf);

        __builtin_amdgcn_s_setprio(1);
        #pragma unroll
        for (int mf = 0; mf < 4; ++mf)
            #pragma unroll
            for (int nf = 0; nf < NF; ++nf)
                acc[mf][nf] = __builtin_amdgcn_mfma_f32_16x16x32_bf16(alo[mf], bA[nf], acc[mf][nf], 0, 0, 0);
        __builtin_amdgcn_s_setprio(0);

        if (s + 1 < NT) {
            const int NS = (SL + 1) & 3;
            const char* nA = smem + NS * 16384;
            const char* nB = smem + 65536 + NS * SB;
            #pragma unroll
            for (int mf = 0; mf < 4; ++mf) alo[mf] = rdA(nA, wm * 8 + mf);
            #pragma unroll
            for (int nf = 0; nf < NF; ++nf) bB[nf] = rdA(nB, wn * NF + nf);
        }

        __builtin_amdgcn_s_setprio(1);
        #pragma unroll
        for (int mf = 0; mf < 4; ++mf)
            #pragma unroll
            for (int nf = 0; nf < NF; ++nf)
                acc[4 + mf][nf] = __builtin_amdgcn_mfma_f32_16x16x32_bf16(ahi[mf], bA[nf], acc[4 + mf][nf], 0, 0, 0);
        __builtin_amdgcn_s_setprio(0);

        MEMFENCE;
        if (s + 3 < NT) {
            if (NF == 4) asm volatile("s_waitcnt vmcnt(4)" ::: "memory");
            else         asm volatile("s_waitcnt vmcnt(3)" ::: "memory");
        } else {
            asm volatile("s_waitcnt vmcnt(0)" ::: "memory");
        }
        __builtin_amdgcn_s_barrier();
        MEMFENCE;
    };

    for (int s = 0; s < NT; s += 2) {
        stepBody(s & 3, s, b0, b1);
        stepBody((s + 1) & 3, s + 1, b1, b0);
    }

    const int rb  = m0 + wm * 128 + lkq * 4;
    const int cb0 = n0 + wn * (NF * 16) + lr;
    #pragma unroll
    for (int mf = 0; mf < 8; ++mf) {
        #pragma unroll
        for (int nf = 0; nf < NF; ++nf) {
            const int c = cb0 + nf * 16;
            #pragma unroll
            for (int r = 0; r < 4; ++r) {
                const int rw = rb + mf * 16 + r;
                const size_t ix = (size_t)rw * ldc + c;
                const float v = acc[mf][nf][r];
                if (EPI == 0) {
                    ((bf16*)Cp + zb * sC)[ix] = (bf16)(alpha * v);
                } else {   // EPI == 3: U + H
                    const float u = v + aux1[c];
                    const float sg = 1.f / (1.f + __expf(-u));
                    const float dd = sg * (1.f + u * (1.f - sg));
                    ((bf16*)Cp)[ix] = (bf16)(dd * aux2[c]);
                    ((bf16*)aux3)[ix] = (bf16)v;   // H = AO@W1 (pre-bias)
                }
            }
        }
    }
}

// ---------------- fp32 -> bf16 cast (DN) and/or transposed cast (DT) ----------------
template<bool DN, bool DT>
__global__ __launch_bounds__(256)
void transcast_k(const float* __restrict__ in, bf16* __restrict__ outN,
                 bf16* __restrict__ outT, int R, int C)
{
    __shared__ float ts[64][65];
    const int t = threadIdx.x;
    const int c0 = blockIdx.x * 64, r0 = blockIdx.y * 64;
    const size_t zoff = (size_t)blockIdx.z * R * C;

    const int rr = t >> 2, cc = (t & 3) * 16;
    float4 f[4];
    const float* src = in + zoff + (size_t)(r0 + rr) * C + c0 + cc;
    #pragma unroll
    for (int i = 0; i < 4; ++i) f[i] = *(const float4*)(src + 4 * i);

    if (DN) {
        bf16x8 h0, h1;
        #pragma unroll
        for (int i = 0; i < 2; ++i) {
            h0[i*4+0] = (bf16)f[i].x;   h0[i*4+1] = (bf16)f[i].y;
            h0[i*4+2] = (bf16)f[i].z;   h0[i*4+3] = (bf16)f[i].w;
            h1[i*4+0] = (bf16)f[i+2].x; h1[i*4+1] = (bf16)f[i+2].y;
            h1[i*4+2] = (bf16)f[i+2].z; h1[i*4+3] = (bf16)f[i+2].w;
        }
        bf16* dst = outN + zoff + (size_t)(r0 + rr) * C + c0 + cc;
        *(bf16x8*)dst = h0;
        *(bf16x8*)(dst + 8) = h1;
    }
    if (DT) {
        #pragma unroll
        for (int i = 0; i < 4; ++i) {
            ts[rr][cc + 4*i + 0] = f[i].x;
            ts[rr][cc + 4*i + 1] = f[i].y;
            ts[rr][cc + 4*i + 2] = f[i].z;
            ts[rr][cc + 4*i + 3] = f[i].w;
        }
        __syncthreads();
        const int ct = t >> 2, rr4 = (t & 3) * 16;
        bf16x8 o0, o1;
        #pragma unroll
        for (int i = 0; i < 8; ++i) o0[i] = (bf16)ts[rr4 + i][ct];
        #pragma unroll
        for (int i = 0; i < 8; ++i) o1[i] = (bf16)ts[rr4 + 8 + i][ct];
        bf16* dst = outT + zoff + (size_t)(c0 + ct) * R + r0 + rr4;
        *(bf16x8*)dst = o0;
        *(bf16x8*)(dst + 8) = o1;
    }
}

// ---------------- row softmax over 2048-wide rows ----------------
__global__ __launch_bounds__(256)
void softmax_k(const bf16* __restrict__ S, bf16* __restrict__ A)
{
    const size_t row = blockIdx.x;
    const int t = threadIdx.x;
    const int wid = t >> 6, lane = t & 63;
    __shared__ float r1[4], r2[4];

    bf16x8 v = *(const bf16x8*)(S + row * 2048 + t * 8);
    float f[8];
    float mx = -1e30f;
    #pragma unroll
    for (int i = 0; i < 8; ++i) { f[i] = (float)v[i]; mx = fmaxf(mx, f[i]); }
    #pragma unroll
    for (int o = 32; o; o >>= 1) mx = fmaxf(mx, __shfl_xor(mx, o, 64));
    if (!lane) r1[wid] = mx;
    __syncthreads();
    mx = fmaxf(fmaxf(r1[0], r1[1]), fmaxf(r1[2], r1[3]));

    float sum = 0.f;
    #pragma unroll
    for (int i = 0; i < 8; ++i) { f[i] = __expf(f[i] - mx); sum += f[i]; }
    #pragma unroll
    for (int o = 32; o; o >>= 1) sum += __shfl_xor(sum, o, 64);
    if (!lane) r2[wid] = sum;
    __syncthreads();
    sum = r2[0] + r2[1] + r2[2] + r2[3];

    const float inv = 1.f / sum;
    bf16x8 ov;
    #pragma unroll
    for (int i = 0; i < 8; ++i) ov[i] = (bf16)(f[i] * inv);
    *(bf16x8*)(A + row * 2048 + t * 8) = ov;
}

// ---------------- rowdot[r] = dot(U[r,:512], H[r,:512]) — FA-backward delta ----------------
__global__ __launch_bounds__(256)
void rowdot_k(const bf16* __restrict__ U, const bf16* __restrict__ H, float* __restrict__ rd)
{
    const int r = blockIdx.x * 4 + (threadIdx.x >> 6);
    const int lane = threadIdx.x & 63;
    bf16x8 uv = *(const bf16x8*)(U + (size_t)r * 512 + lane * 8);
    bf16x8 hv = *(const bf16x8*)(H + (size_t)r * 512 + lane * 8);
    float d = 0.f;
    #pragma unroll
    for (int i = 0; i < 8; ++i) d += (float)uv[i] * (float)hv[i];
    #pragma unroll
    for (int o = 32; o; o >>= 1) d += __shfl_xor(d, o, 64);
    if (!lane) rd[r] = d;
}

extern "C" void kernel_launch(void* const* d_in, const int* in_sizes, int n_in,
                              void* d_out, int out_size, void* d_ws, size_t ws_size,
                              hipStream_t stream)
{
    const float* Q  = (const float*)d_in[0];
    const float* Km = (const float*)d_in[1];
    const float* V  = (const float*)d_in[2];
    const float* W1 = (const float*)d_in[3];
    const float* b1 = (const float*)d_in[4];
    const float* W2 = (const float*)d_in[5];
    float* out = (float*)d_out;

    // ---- workspace layout (~236 MB, live-range packed) ----
    char* ws = (char*)d_ws;
    bf16* Amat = (bf16*)(ws);                    // R1: A, then dS (in-place)   67.1 MB
    bf16* AO   = (bf16*)(ws + 67108864);         // R2: Kb (pre-GEMM3), then attn_out bf16
    bf16* Kb   = AO;
    bf16* KbT  = (bf16*)(ws + 100663296);        // R3: K^T bf16
    bf16* Vb   = (bf16*)(ws + 134217728);        // R4: V bf16 -> H (after VW1)
    bf16* Hb   = Vb;
    bf16* VbT  = (bf16*)(ws + 167772160);        // R5: V^T bf16 -> U
    bf16* U    = VbT;
    bf16* Qb   = (bf16*)(ws + 201326592);        // R6: Q bf16 -> VW1 [2048][512]/batch
    bf16* VW1b = Qb;
    bf16* W1T  = (bf16*)(ws + 234881024);        // R7: W1^T bf16 [512][1024] (1 MB)
    float* rowdot = (float*)(ws + 235929600);    // R8: rowdot f32 [16384] (64 KB)
    bf16* S    = (bf16*)d_out;                   // S (dead after softmax; d_out reused for out)

    const long sQK = 2048L * 1024;
    const long sS  = 2048L * 2048;
    const long sVW = 2048L * 512;
    dim3 blk(256), blkG(512);

    // ---- prep: bf16 casts / transposes ----
    transcast_k<true,  false><<<dim3(16, 32, 8), blk, 0, stream>>>(Q,  Qb, nullptr, 2048, 1024);
    transcast_k<true,  true ><<<dim3(16, 32, 8), blk, 0, stream>>>(Km, Kb, KbT,     2048, 1024);
    transcast_k<true,  true ><<<dim3(16, 32, 8), blk, 0, stream>>>(V,  Vb, VbT,     2048, 1024);
    transcast_k<false, true ><<<dim3(8,  16, 1), blk, 0, stream>>>(W1, nullptr, W1T, 1024, 512);

    // 1) S = scale * Qb @ Kb^T
    gemm8p<0><<<dim3(8, 8, 8), blkG, 0, stream>>>(
        Qb, Kb, S, 1024, 1024, 1024, 2048, sQK, sQK, sS, 0.03125f, nullptr, nullptr);

    // 1b) VW1 = V @ W1  (B = W1^T; overwrites Qb region — Qb dead after GEMM 1)
    gemm_nc<0, 2><<<dim3(4, 8, 8), blkG, 0, stream>>>(
        Vb, W1T, VW1b, 1024, 1024, 1024, 512, sQK, 0, sVW, 1.0f, nullptr, nullptr, nullptr);

    // 2) A = row-softmax(S)
    softmax_k<<<dim3(16384), blk, 0, stream>>>(S, Amat);

    // 3) attn_out = A @ V   (B = V^T [1024][2048]; overwrites Kb region with AO)
    gemm8p<0><<<dim3(4, 8, 8), blkG, 0, stream>>>(
        Amat, VbT, AO, 2048, 2048, 2048, 1024, sS, sQK, sQK, 1.0f, nullptr, nullptr);

    // 4) U = silu'(AO @ W1 + b1) * w2 ; H = AO @ W1   (H into dead Vb region)
    gemm_nc<3, 2><<<dim3(4, 64, 1), blkG, 0, stream>>>(
        AO, W1T, U, 1024, 1024, 1024, 512, 0, 0, 0, 1.0f, b1, W2, Hb);

    // 5) rowdot[n] = dot(U[n], H[n])   (= rowsum(A .* dA), FA-backward identity)
    rowdot_k<<<dim3(4096), blk, 0, stream>>>(U, Hb, rowdot);

    // 6) dS = A .* (U @ VW1^T - rowdot)  — K=512 GEMM, epilogue-fused, in-place into Amat
    gemm8p<1><<<dim3(8, 8, 8), blkG, 0, stream>>>(
        U, VW1b, Amat, 512, 512, 512, 2048, sVW, sVW, sS, 1.0f, rowdot, Amat);

    // 7) out = V + attn_out - (eps*scale) * dS @ K   (B = K^T [1024][2048])
    gemm8p<2><<<dim3(4, 8, 8), blkG, 0, stream>>>(
        Amat, KbT, out, 2048, 2048, 2048, 1024, sS, sQK, sQK, 0.03f * 0.03125f, V, AO);
}

// Round 3
// 420.293 us; speedup vs baseline: 1.0387x; 1.0387x over previous
//
#include <hip/hip_runtime.h>

typedef __bf16 bf16;
typedef __attribute__((ext_vector_type(8))) __bf16 bf16x8;
typedef __attribute__((ext_vector_type(4))) float f32x4;

#define MEMFENCE asm volatile("" ::: "memory")

// async global->LDS, 16B per lane; LDS dest = wave-uniform base + lane*16
__device__ __forceinline__ void gload16(const bf16* g, bf16* l) {
    __builtin_amdgcn_global_load_lds(
        (const __attribute__((address_space(1))) void*)g,
        (__attribute__((address_space(3))) void*)l,
        16, 0, 0);
}

// ============ 256x256 8-wave bf16 NT GEMM, BK=64, 4-seg cross-fed pipeline (R3) ============
// LDS: A bufs {0,1,2} at a*32768 (96K, triple), B bufs {0,1} at 98304+p*32768 (64K, double).
// Quadrant order per tile u: (0,2)->(0,0)->(4,0)->(4,2). Register rotation (64 VGPR total):
//   a[4][2] holds al(u) segs1-2, then ah(u) segs3-4, then al(u+1) (pre-read seg4).
//   bh[2][2] holds bh(u) (pre-read prev seg4); bl[2][2] read seg1.
// Each seg: [stage 2 gloads][ds_reads for LATER quadrant][16 MFMA] -- same-seg reads have no
// dep on the MFMA cluster, so the LDS pipe drains WHILE the MFMA pipe runs.
// Barriers: 2/tile (end seg2, end seg4).
// RACE INVARIANT (R2 bug fix): every cross-wave LDS read must sit after a {per-wave vmcnt
// confirming that data -> s_barrier} pair.  Single wait per tile, at end of seg2 (W1):
//   steady (st2): queue [A(u+1)4, B(u+1)4, A(u+2)4] -> vmcnt(4) confirms A(u+1) AND B(u+1);
//   barrier1 then publishes both to all waves BEFORE the seg4 pre-reads of al(u+1)/bh(u+1).
//   Tail u=NTt-2: queue [A(u+1)4, B(u+1)4] -> vmcnt(0).  Last tile: nothing outstanding.
// WAR fences: barrier1 protects B-buf p (bl/bh(u) reads done pre-barrier1; stgB(u+2) at seg3);
//   barrier2 protects A-buf rotation (ah(u) reads done pre-barrier2; stgA(u+3) at next seg1).
// st_16x32 swizzle: phys = off ^ (((off>>9)&1)<<5); inverse-swizzled global source.
// EPI 0: bf16 C = alpha*acc
// EPI 1: bf16 C[ix] = aux3[ix] * (acc - aux1[zb*2048+row])      (dS = A*(dA-rowdot), in-place ok)
// EPI 2: f32  C = aux1[ix] + (float)aux3[ix] - alpha*acc        (out = V + AO - eps*scale*dQacc)
template<int EPI>
__global__ __launch_bounds__(512, 1)
void gemm8p(const bf16* __restrict__ A, const bf16* __restrict__ Bm,
            void* __restrict__ Cp, int Kdim, int lda, int ldb, int ldc,
            long sA, long sB, long sC, float alpha,
            const float* __restrict__ aux1, const bf16* __restrict__ aux3)
{
    __shared__ __align__(16) char smem[163840];

    // XCD-aware bijective swizzle (ntot % 8 == 0 for all launches)
    const int gx = gridDim.x, gy = gridDim.y;
    int lin = blockIdx.x + gx * (blockIdx.y + gy * blockIdx.z);
    const int q = (gx * gy * gridDim.z) >> 3;
    lin = (lin & 7) * q + (lin >> 3);
    const int bx = lin % gx;
    const int rem0 = lin / gx;
    const int by = rem0 % gy;
    const int bz = rem0 / gy;

    const int t0 = threadIdx.x;
    const int w = t0 >> 6, lane = t0 & 63;
    const int wm = w >> 2, wn = w & 3;          // 2 x 4 wave grid; per-wave C = 128 x 64
    const int m0 = by * 256, n0 = bx * 256;
    const long zb = bz;

    const bf16* Ab = A  + zb * sA + (size_t)m0 * lda;
    const bf16* Bb = Bm + zb * sB + (size_t)n0 * ldb;

    // staging lane coords: wave w stages subtiles {w, 8+w} of a 128-row half-tile
    const int sr16 = lane >> 2;
    const int sce  = ((((lane & 3) << 4) ^ (((lane >> 5) & 1) << 5))) >> 1; // inv-swizzled col
    const int r0s = (w >> 1) * 16 + sr16;
    const int c0s = (w & 1) * 32 + sce;
    const bf16* gA0 = Ab + (size_t)r0s * lda + c0s;
    const bf16* gA1 = Ab + (size_t)(128 + r0s) * lda + c0s;
    const bf16* gB0 = Bb + (size_t)r0s * ldb + c0s;
    const bf16* gB1 = Bb + (size_t)(128 + r0s) * ldb + c0s;
    const size_t a64 = (size_t)64 * lda, b64 = (size_t)64 * ldb;
    const int ldsW0 = w * 1024, ldsW1 = (8 + w) * 1024;

    // fragment-read bases (16x16x32 layout)
    const int lr = lane & 15, lkq = lane >> 4;
    const int phx = ((lane >> 3) & 1) << 5;
    const int frag_base = (lr * 64 + lkq * 16) ^ phx;
    const char* aR = smem + wm * 16384 + frag_base;                    // + aOff + sub*1024
    const char* bR = smem + 98304 + (wn >> 1) * 16384 + (wn & 1) * 8192 + frag_base; // + p*32768

    f32x4 acc[8][4] = {};
    const int NTt = Kdim >> 6;                  // K-tiles of 64 (8/16/32, always even)

    auto stgA = [&](int h, int u, int off) {
        char* L = smem + off + h * 16384;
        const bf16* g = h ? gA1 : gA0;
        gload16(g + (size_t)u * 64,        (bf16*)(L + ldsW0));
        gload16(g + a64 + (size_t)u * 64,  (bf16*)(L + ldsW1));
    };
    auto stgB = [&](int h, int u, int p) {
        char* L = smem + 98304 + p * 32768 + h * 16384;
        const bf16* g = h ? gB1 : gB0;
        gload16(g + (size_t)u * 64,        (bf16*)(L + ldsW0));
        gload16(g + b64 + (size_t)u * 64,  (bf16*)(L + ldsW1));
    };

    // ---- prologue: A(0),B(0),A(1),B(1); vmcnt(8) confirms A(0),B(0); barrier publishes ----
    stgA(0, 0, 0);     stgA(1, 0, 0);     stgB(0, 0, 0); stgB(1, 0, 0);
    stgA(0, 1, 32768); stgA(1, 1, 32768); stgB(0, 1, 1); stgB(1, 1, 1);
    asm volatile("s_waitcnt vmcnt(8)" ::: "memory");
    __builtin_amdgcn_s_barrier();
    MEMFENCE;

    bf16x8 a[4][2], bl[2][2], bh[2][2];
    // pre-read al(0) and bh(0)
    #pragma unroll
    for (int mf = 0; mf < 4; ++mf)
        #pragma unroll
        for (int ks = 0; ks < 2; ++ks)
            a[mf][ks] = *(const bf16x8*)(aR + (mf * 2 + ks) * 1024);
    #pragma unroll
    for (int nf = 0; nf < 2; ++nf)
        #pragma unroll
        for (int ks = 0; ks < 2; ++ks)
            bh[nf][ks] = *(const bf16x8*)(bR + ((2 + nf) * 2 + ks) * 1024);

#define QUADQ(MFB, NFB, AARR, BARR)                                                     \
    __builtin_amdgcn_s_setprio(1);                                                      \
    _Pragma("unroll")                                                                   \
    for (int ks = 0; ks < 2; ++ks)                                                      \
        _Pragma("unroll")                                                               \
        for (int mf = 0; mf < 4; ++mf)                                                  \
            _Pragma("unroll")                                                           \
            for (int nf = 0; nf < 2; ++nf)                                              \
                acc[(MFB) + mf][(NFB) + nf] = __builtin_amdgcn_mfma_f32_16x16x32_bf16(  \
                    AARR[mf][ks], BARR[nf][ks], acc[(MFB) + mf][(NFB) + nf], 0, 0, 0);  \
    __builtin_amdgcn_s_setprio(0);

    int aOff = 0, aOff1 = 32768, sOff = 65536;  // A(u), A(u+1), stage A(u+2)
    for (int u = 0; u < NTt; ++u) {
        const int p = u & 1;
        const char* aP  = aR + aOff;
        const char* aP1 = aR + aOff1;
        const char* bP  = bR + p * 32768;
        const char* bP1 = bR + (p ^ 1) * 32768;
        const bool st2 = (u + 2 < NTt), nx = (u + 1 < NTt);

        // ---- seg1: Q(0,2)=al*bh ; read bl(u) [4]; stage A0(u+2) ----
        if (st2) stgA(0, u + 2, sOff);
        #pragma unroll
        for (int nf = 0; nf < 2; ++nf)
            #pragma unroll
            for (int ks = 0; ks < 2; ++ks)
                bl[nf][ks] = *(const bf16x8*)(bP + (nf * 2 + ks) * 1024);
        QUADQ(0, 2, a, bh)

        // ---- seg2: Q(0,0)=al*bl ; a <- ah(u) [8]; stage A1(u+2); W1; barrier1 ----
        if (st2) stgA(1, u + 2, sOff);
        QUADQ(0, 0, a, bl)
        #pragma unroll
        for (int mf = 0; mf < 4; ++mf)
            #pragma unroll
            for (int ks = 0; ks < 2; ++ks)
                a[mf][ks] = *(const bf16x8*)(aP + ((4 + mf) * 2 + ks) * 1024);
        MEMFENCE;
        if (st2)     asm volatile("s_waitcnt vmcnt(4)" ::: "memory");  // A(u+1)+B(u+1)
        else if (nx) asm volatile("s_waitcnt vmcnt(0)" ::: "memory");  // tail: confirm both
        __builtin_amdgcn_s_barrier();
        MEMFENCE;

        // ---- seg3: Q(4,0)=ah*bl ; stage B0(u+2) ----
        if (st2) stgB(0, u + 2, p);
        QUADQ(4, 0, a, bl)

        // ---- seg4: Q(4,2)=ah*bh ; a <- al(u+1) [8]; bh <- bh(u+1) [4]; barrier2 ----
        if (st2) stgB(1, u + 2, p);
        QUADQ(4, 2, a, bh)
        if (nx) {
            #pragma unroll
            for (int mf = 0; mf < 4; ++mf)
                #pragma unroll
                for (int ks = 0; ks < 2; ++ks)
                    a[mf][ks] = *(const bf16x8*)(aP1 + (mf * 2 + ks) * 1024);
            #pragma unroll
            for (int nf = 0; nf < 2; ++nf)
                #pragma unroll
                for (int ks = 0; ks < 2; ++ks)
                    bh[nf][ks] = *(const bf16x8*)(bP1 + ((2 + nf) * 2 + ks) * 1024);
        }
        MEMFENCE;
        __builtin_amdgcn_s_barrier();
        MEMFENCE;

        const int tmp = aOff; aOff = aOff1; aOff1 = sOff; sOff = tmp;
    }
#undef QUADQ

    // ---- epilogue: D layout col=lane&15, row=(lane>>4)*4+reg ----
    const int rb  = m0 + wm * 128 + lkq * 4;
    const int cb0 = n0 + wn * 64 + lr;
    #pragma unroll
    for (int mf = 0; mf < 8; ++mf) {
        #pragma unroll
        for (int r = 0; r < 4; ++r) {
            const int rw = rb + mf * 16 + r;
            float rd = 0.f;
            if (EPI == 1) rd = aux1[zb * 2048 + rw];
            #pragma unroll
            for (int nf = 0; nf < 4; ++nf) {
                const int c = cb0 + nf * 16;
                const size_t ix = (size_t)rw * ldc + c;
                const float v = acc[mf][nf][r];
                if (EPI == 0) {
                    ((bf16*)Cp + zb * sC)[ix] = (bf16)(alpha * v);
                } else if (EPI == 1) {
                    bf16* Cb = (bf16*)Cp + zb * sC;
                    const bf16* Am = aux3 + zb * sC;
                    Cb[ix] = (bf16)((float)Am[ix] * (v - rd));
                } else {
                    float* C = (float*)Cp + zb * sC;
                    const float* Vv = aux1 + zb * sC;
                    const bf16* AOv = aux3 + zb * sC;
                    C[ix] = Vv[ix] + (float)AOv[ix] - alpha * v;
                }
            }
        }
    }
}

// ===== round-6 engine: 256 x (64*NF) quad-slot BK=32 cross-step =====
// EPI 0: bf16 C = alpha*acc
// EPI 3: bf16 C = silu'(acc + aux1[col]) * aux2[col];  H[ix] = (bf16)acc  (H via aux3, cast)
template<int EPI, int NF>
__global__ __launch_bounds__(512, 1)
void gemm_nc(const bf16* __restrict__ A, const bf16* __restrict__ Bm,
             void* __restrict__ Cp, int Kdim, int lda, int ldb, int ldc,
             long sA, long sB, long sC, float alpha,
             const float* __restrict__ aux1, const float* __restrict__ aux2,
             const bf16* __restrict__ aux3)
{
    constexpr int SB = NF * 4096;
    __shared__ __align__(16) char smem[65536 + 4 * SB];

    const int gx = gridDim.x, gy = gridDim.y;
    int lin = blockIdx.x + gx * (blockIdx.y + gy * blockIdx.z);
    const int q = (gx * gy * gridDim.z) >> 3;
    lin = (lin & 7) * q + (lin >> 3);
    const int bx = lin % gx;
    const int rem0 = lin / gx;
    const int by = rem0 % gy;
    const int bz = rem0 / gy;

    const int t0 = threadIdx.x;
    const int w = t0 >> 6, lane = t0 & 63;
    const int wm = w >> 2, wn = w & 3;
    const int m0 = by * 256, n0 = bx * (64 * NF);
    const long zb = bz;

    const bf16* Ab = A  + zb * sA + (size_t)m0 * lda;
    const bf16* Bb = Bm + zb * sB + (size_t)n0 * ldb;

    const int sr16 = lane >> 2;
    const int sce  = ((((lane & 3) << 4) ^ (((lane >> 5) & 1) << 5))) >> 1;
    const int stg0 = w * 2, stg1 = w * 2 + 1;
    const bf16* pA0 = Ab + (size_t)(stg0 * 16 + sr16) * lda + sce;
    const bf16* pA1 = Ab + (size_t)(stg1 * 16 + sr16) * lda + sce;
    const bf16* pB0 = Bb + (size_t)((NF == 4 ? stg0 : w) * 16 + sr16) * ldb + sce;
    const bf16* pB1 = Bb + (size_t)(stg1 * 16 + sr16) * ldb + sce;

    const int lr = lane & 15, lkq = lane >> 4;
    const int phx = ((lane >> 3) & 1) << 5;
    const int frag_base = lr * 64 + lkq * 16;

    f32x4 acc[8][NF] = {};
    const int NT = Kdim >> 5;

    auto issueSlot = [&](int p) {
        char* lA = smem + (p & 3) * 16384;
        char* lB = smem + 65536 + (p & 3) * SB;
        const int kt = p << 5;
        gload16(pA0 + kt, (bf16*)(lA + stg0 * 1024));
        gload16(pA1 + kt, (bf16*)(lA + stg1 * 1024));
        if (NF == 4) {
            gload16(pB0 + kt, (bf16*)(lB + stg0 * 1024));
            gload16(pB1 + kt, (bf16*)(lB + stg1 * 1024));
        } else {
            gload16(pB0 + kt, (bf16*)(lB + w * 1024));
        }
    };
    auto rdA = [&](const char* base, int sub) {
        return *(const bf16x8*)(base + (((sub << 10) + frag_base) ^ phx));
    };

    issueSlot(0); issueSlot(1); issueSlot(2);
    if (NF == 4) asm volatile("s_waitcnt vmcnt(4)" ::: "memory");
    else         asm volatile("s_waitcnt vmcnt(3)" ::: "memory");
    __builtin_amdgcn_s_barrier();
    MEMFENCE;

    bf16x8 alo[4], ahi[4], b0[NF], b1[NF];
    {
        const char* cA = smem;
        const char* cB = smem + 65536;
        #pragma unroll
        for (int mf = 0; mf < 4; ++mf) alo[mf] = rdA(cA, wm * 8 + mf);
        #pragma unroll
        for (int nf = 0; nf < NF; ++nf) b0[nf] = rdA(cB, wn * NF + nf);
    }

    auto stepBody = [&](int SL, int s, bf16x8 (&bA)[NF], bf16x8 (&bB)[NF]) {
        if (s + 3 < NT) issueSlot(s + 3);
        const char* cA = smem + SL * 16384;
        #pragma unroll
        for (int mf = 0; mf < 4; ++mf) ahi[mf] = rdA(cA, wm * 8 + 4 + mf);

        __builtin_amdgcn_s_setprio(1);
        #pragma unroll
        for (int mf = 0; mf < 4; ++mf)
            #pragma unroll
            for (int nf = 0; nf < NF; ++nf)
                acc[mf][nf] = __builtin_amdgcn_mfma_f32_16x16x32_bf16(alo[mf], bA[nf], acc[mf][nf], 0, 0, 0);
        __builtin_amdgcn_s_setprio(0);

        if (s + 1 < NT) {
            const int NS = (SL + 1) & 3;
            const char* nA = smem + NS * 16384;
            const char* nB = smem + 65536 + NS * SB;
            #pragma unroll
            for (int mf = 0; mf < 4; ++mf) alo[mf] = rdA(nA, wm * 8 + mf);
            #pragma unroll
            for (int nf = 0; nf < NF; ++nf) bB[nf] = rdA(nB, wn * NF + nf);
        }

        __builtin_amdgcn_s_setprio(1);
        #pragma unroll
        for (int mf = 0; mf < 4; ++mf)
            #pragma unroll
            for (int nf = 0; nf < NF; ++nf)
                acc[4 + mf][nf] = __builtin_amdgcn_mfma_f32_16x16x32_bf16(ahi[mf], bA[nf], acc[4 + mf][nf], 0, 0, 0);
        __builtin_amdgcn_s_setprio(0);

        MEMFENCE;
        if (s + 3 < NT) {
            if (NF == 4) asm volatile("s_waitcnt vmcnt(4)" ::: "memory");
            else         asm volatile("s_waitcnt vmcnt(3)" ::: "memory");
        } else {
            asm volatile("s_waitcnt vmcnt(0)" ::: "memory");
        }
        __builtin_amdgcn_s_barrier();
        MEMFENCE;
    };

    for (int s = 0; s < NT; s += 2) {
        stepBody(s & 3, s, b0, b1);
        stepBody((s + 1) & 3, s + 1, b1, b0);
    }

    const int rb  = m0 + wm * 128 + lkq * 4;
    const int cb0 = n0 + wn * (NF * 16) + lr;
    #pragma unroll
    for (int mf = 0; mf < 8; ++mf) {
        #pragma unroll
        for (int nf = 0; nf < NF; ++nf) {
            const int c = cb0 + nf * 16;
            #pragma unroll
            for (int r = 0; r < 4; ++r) {
                const int rw = rb + mf * 16 + r;
                const size_t ix = (size_t)rw * ldc + c;
                const float v = acc[mf][nf][r];
                if (EPI == 0) {
                    ((bf16*)Cp + zb * sC)[ix] = (bf16)(alpha * v);
                } else {   // EPI == 3: U + H
                    const float u = v + aux1[c];
                    const float sg = 1.f / (1.f + __expf(-u));
                    const float dd = sg * (1.f + u * (1.f - sg));
                    ((bf16*)Cp)[ix] = (bf16)(dd * aux2[c]);
                    ((bf16*)aux3)[ix] = (bf16)v;   // H = AO@W1 (pre-bias)
                }
            }
        }
    }
}

// ---------------- fp32 -> bf16 cast (DN) and/or transposed cast (DT) ----------------
template<bool DN, bool DT>
__global__ __launch_bounds__(256)
void transcast_k(const float* __restrict__ in, bf16* __restrict__ outN,
                 bf16* __restrict__ outT, int R, int C)
{
    __shared__ float ts[64][65];
    const int t = threadIdx.x;
    const int c0 = blockIdx.x * 64, r0 = blockIdx.y * 64;
    const size_t zoff = (size_t)blockIdx.z * R * C;

    const int rr = t >> 2, cc = (t & 3) * 16;
    float4 f[4];
    const float* src = in + zoff + (size_t)(r0 + rr) * C + c0 + cc;
    #pragma unroll
    for (int i = 0; i < 4; ++i) f[i] = *(const float4*)(src + 4 * i);

    if (DN) {
        bf16x8 h0, h1;
        #pragma unroll
        for (int i = 0; i < 2; ++i) {
            h0[i*4+0] = (bf16)f[i].x;   h0[i*4+1] = (bf16)f[i].y;
            h0[i*4+2] = (bf16)f[i].z;   h0[i*4+3] = (bf16)f[i].w;
            h1[i*4+0] = (bf16)f[i+2].x; h1[i*4+1] = (bf16)f[i+2].y;
            h1[i*4+2] = (bf16)f[i+2].z; h1[i*4+3] = (bf16)f[i+2].w;
        }
        bf16* dst = outN + zoff + (size_t)(r0 + rr) * C + c0 + cc;
        *(bf16x8*)dst = h0;
        *(bf16x8*)(dst + 8) = h1;
    }
    if (DT) {
        #pragma unroll
        for (int i = 0; i < 4; ++i) {
            ts[rr][cc + 4*i + 0] = f[i].x;
            ts[rr][cc + 4*i + 1] = f[i].y;
            ts[rr][cc + 4*i + 2] = f[i].z;
            ts[rr][cc + 4*i + 3] = f[i].w;
        }
        __syncthreads();
        const int ct = t >> 2, rr4 = (t & 3) * 16;
        bf16x8 o0, o1;
        #pragma unroll
        for (int i = 0; i < 8; ++i) o0[i] = (bf16)ts[rr4 + i][ct];
        #pragma unroll
        for (int i = 0; i < 8; ++i) o1[i] = (bf16)ts[rr4 + 8 + i][ct];
        bf16* dst = outT + zoff + (size_t)(c0 + ct) * R + r0 + rr4;
        *(bf16x8*)dst = o0;
        *(bf16x8*)(dst + 8) = o1;
    }
}

// ---------------- row softmax over 2048-wide rows ----------------
__global__ __launch_bounds__(256)
void softmax_k(const bf16* __restrict__ S, bf16* __restrict__ A)
{
    const size_t row = blockIdx.x;
    const int t = threadIdx.x;
    const int wid = t >> 6, lane = t & 63;
    __shared__ float r1[4], r2[4];

    bf16x8 v = *(const bf16x8*)(S + row * 2048 + t * 8);
    float f[8];
    float mx = -1e30f;
    #pragma unroll
    for (int i = 0; i < 8; ++i) { f[i] = (float)v[i]; mx = fmaxf(mx, f[i]); }
    #pragma unroll
    for (int o = 32; o; o >>= 1) mx = fmaxf(mx, __shfl_xor(mx, o, 64));
    if (!lane) r1[wid] = mx;
    __syncthreads();
    mx = fmaxf(fmaxf(r1[0], r1[1]), fmaxf(r1[2], r1[3]));

    float sum = 0.f;
    #pragma unroll
    for (int i = 0; i < 8; ++i) { f[i] = __expf(f[i] - mx); sum += f[i]; }
    #pragma unroll
    for (int o = 32; o; o >>= 1) sum += __shfl_xor(sum, o, 64);
    if (!lane) r2[wid] = sum;
    __syncthreads();
    sum = r2[0] + r2[1] + r2[2] + r2[3];

    const float inv = 1.f / sum;
    bf16x8 ov;
    #pragma unroll
    for (int i = 0; i < 8; ++i) ov[i] = (bf16)(f[i] * inv);
    *(bf16x8*)(A + row * 2048 + t * 8) = ov;
}

// ---------------- rowdot[r] = dot(U[r,:512], H[r,:512]) — FA-backward delta ----------------
__global__ __launch_bounds__(256)
void rowdot_k(const bf16* __restrict__ U, const bf16* __restrict__ H, float* __restrict__ rd)
{
    const int r = blockIdx.x * 4 + (threadIdx.x >> 6);
    const int lane = threadIdx.x & 63;
    bf16x8 uv = *(const bf16x8*)(U + (size_t)r * 512 + lane * 8);
    bf16x8 hv = *(const bf16x8*)(H + (size_t)r * 512 + lane * 8);
    float d = 0.f;
    #pragma unroll
    for (int i = 0; i < 8; ++i) d += (float)uv[i] * (float)hv[i];
    #pragma unroll
    for (int o = 32; o; o >>= 1) d += __shfl_xor(d, o, 64);
    if (!lane) rd[r] = d;
}

extern "C" void kernel_launch(void* const* d_in, const int* in_sizes, int n_in,
                              void* d_out, int out_size, void* d_ws, size_t ws_size,
                              hipStream_t stream)
{
    const float* Q  = (const float*)d_in[0];
    const float* Km = (const float*)d_in[1];
    const float* V  = (const float*)d_in[2];
    const float* W1 = (const float*)d_in[3];
    const float* b1 = (const float*)d_in[4];
    const float* W2 = (const float*)d_in[5];
    float* out = (float*)d_out;

    // ---- workspace layout (~236 MB, live-range packed) ----
    char* ws = (char*)d_ws;
    bf16* Amat = (bf16*)(ws);                    // R1: A, then dS (in-place)   67.1 MB
    bf16* AO   = (bf16*)(ws + 67108864);         // R2: Kb (pre-GEMM3), then attn_out bf16
    bf16* Kb   = AO;
    bf16* KbT  = (bf16*)(ws + 100663296);        // R3: K^T bf16
    bf16* Vb   = (bf16*)(ws + 134217728);        // R4: V bf16 -> H (after VW1)
    bf16* Hb   = Vb;
    bf16* VbT  = (bf16*)(ws + 167772160);        // R5: V^T bf16 -> U
    bf16* U    = VbT;
    bf16* Qb   = (bf16*)(ws + 201326592);        // R6: Q bf16 -> VW1 [2048][512]/batch
    bf16* VW1b = Qb;
    bf16* W1T  = (bf16*)(ws + 234881024);        // R7: W1^T bf16 [512][1024] (1 MB)
    float* rowdot = (float*)(ws + 235929600);    // R8: rowdot f32 [16384] (64 KB)
    bf16* S    = (bf16*)d_out;                   // S (dead after softmax; d_out reused for out)

    const long sQK = 2048L * 1024;
    const long sS  = 2048L * 2048;
    const long sVW = 2048L * 512;
    dim3 blk(256), blkG(512);

    // ---- prep: bf16 casts / transposes ----
    transcast_k<true,  false><<<dim3(16, 32, 8), blk, 0, stream>>>(Q,  Qb, nullptr, 2048, 1024);
    transcast_k<true,  true ><<<dim3(16, 32, 8), blk, 0, stream>>>(Km, Kb, KbT,     2048, 1024);
    transcast_k<true,  true ><<<dim3(16, 32, 8), blk, 0, stream>>>(V,  Vb, VbT,     2048, 1024);
    transcast_k<false, true ><<<dim3(8,  16, 1), blk, 0, stream>>>(W1, nullptr, W1T, 1024, 512);

    // 1) S = scale * Qb @ Kb^T
    gemm8p<0><<<dim3(8, 8, 8), blkG, 0, stream>>>(
        Qb, Kb, S, 1024, 1024, 1024, 2048, sQK, sQK, sS, 0.03125f, nullptr, nullptr);

    // 1b) VW1 = V @ W1  (B = W1^T; overwrites Qb region — Qb dead after GEMM 1)
    gemm_nc<0, 2><<<dim3(4, 8, 8), blkG, 0, stream>>>(
        Vb, W1T, VW1b, 1024, 1024, 1024, 512, sQK, 0, sVW, 1.0f, nullptr, nullptr, nullptr);

    // 2) A = row-softmax(S)
    softmax_k<<<dim3(16384), blk, 0, stream>>>(S, Amat);

    // 3) attn_out = A @ V   (B = V^T [1024][2048]; overwrites Kb region with AO)
    gemm8p<0><<<dim3(4, 8, 8), blkG, 0, stream>>>(
        Amat, VbT, AO, 2048, 2048, 2048, 1024, sS, sQK, sQK, 1.0f, nullptr, nullptr);

    // 4) U = silu'(AO @ W1 + b1) * w2 ; H = AO @ W1   (H into dead Vb region)
    gemm_nc<3, 2><<<dim3(4, 64, 1), blkG, 0, stream>>>(
        AO, W1T, U, 1024, 1024, 1024, 512, 0, 0, 0, 1.0f, b1, W2, Hb);

    // 5) rowdot[n] = dot(U[n], H[n])   (= rowsum(A .* dA), FA-backward identity)
    rowdot_k<<<dim3(4096), blk, 0, stream>>>(U, Hb, rowdot);

    // 6) dS = A .* (U @ VW1^T - rowdot)  — K=512 GEMM, epilogue-fused, in-place into Amat
    gemm8p<1><<<dim3(8, 8, 8), blkG, 0, stream>>>(
        U, VW1b, Amat, 512, 512, 512, 2048, sVW, sVW, sS, 1.0f, rowdot, Amat);

    // 7) out = V + attn_out - (eps*scale) * dS @ K   (B = K^T [1024][2048])
    gemm8p<2><<<dim3(4, 8, 8), blkG, 0, stream>>>(
        Amat, KbT, out, 2048, 2048, 2048, 1024, sS, sQK, sQK, 0.03f * 0.03125f, V, AO);
}